// Round 9
// baseline (1120.715 us; speedup 1.0000x reference)
//
#include <hip/hip_runtime.h>

#define NRELS 8
typedef __attribute__((ext_vector_type(8))) short s16x8;
typedef __attribute__((ext_vector_type(4))) float f32x4;
typedef unsigned short u16;
typedef unsigned int u32;

__device__ __forceinline__ u16 f2bf(float v) {
    unsigned u = __float_as_uint(v);
    u += 0x7FFFu + ((u >> 16) & 1u);
    return (u16)(u >> 16);
}
__device__ __forceinline__ float bf2f(u16 h) {
    return __uint_as_float(((unsigned)h) << 16);
}
__device__ __forceinline__ float eluf(float x) { return x > 0.f ? x : __expf(x) - 1.f; }

// ---------------- weight prep: fragment-major bf16 W (9 col-tiles) + permuted bias ----
__global__ void prep_weights(const float* __restrict__ Ws1, const float* __restrict__ Wd1,
                             const float* __restrict__ as1, const float* __restrict__ ad1,
                             const float* __restrict__ b1,
                             const float* __restrict__ Ws2, const float* __restrict__ Wd2,
                             const float* __restrict__ as2, const float* __restrict__ ad2,
                             const float* __restrict__ b2,
                             u16* __restrict__ Wfrag, float* __restrict__ bperm) {
    const int bid = blockIdx.x;
    const int layer = bid >> 3, r = bid & 7, r1 = r ^ 1;
    const float* Ws  = (layer ? Ws2 : Ws1) + (size_t)r  * 16384;
    const float* asp = (layer ? as2 : as1) + r  * 128;
    const float* Wdr = (layer ? Wd2 : Wd1) + (size_t)r1 * 16384;
    const float* adr = (layer ? ad2 : ad1) + r1 * 128;
    const float* bb  = (layer ? b2  : b1 ) + r  * 128;
    u16* wf = Wfrag + (size_t)bid * 18432;
    for (int f = threadIdx.x; f < 18432; f += blockDim.x) {
        int be   = f & 7;
        int lane = (f >> 3) & 63;
        int kc   = (f >> 9) & 3;
        int ct   = f >> 11;
        int k    = kc * 32 + (lane >> 4) * 8 + be;
        int krow = layer ? (((k & 7) << 4) | (k >> 3)) : k;
        int c    = lane & 15;
        float val;
        if (ct < 8) {
            val = Ws[(size_t)krow * 128 + ct * 16 + c];
        } else if (c < 4) {
            float s = 0.f;
            #pragma unroll
            for (int cc = 0; cc < 32; ++cc) s += Ws[(size_t)krow * 128 + c * 32 + cc] * asp[c * 32 + cc];
            val = s;
        } else if (c < 8) {
            int h = c - 4;
            float s = 0.f;
            #pragma unroll
            for (int cc = 0; cc < 32; ++cc) s += Wdr[(size_t)krow * 128 + h * 32 + cc] * adr[h * 32 + cc];
            val = s;
        } else {
            val = 0.f;
        }
        wf[f] = f2bf(val);
    }
    if (threadIdx.x < 128) {
        int p = threadIdx.x;
        bperm[bid * 128 + p] = bb[((p & 7) << 4) | (p >> 3)];
    }
}

// ---------------- b0sum: per-layer sum of biases of relations {1,3,5,7} ----------------
__global__ void prep_bsum(const float* __restrict__ bperm, float* __restrict__ b0sum) {
    int layer = blockIdx.x, p = threadIdx.x;
    float s = bperm[(layer * 8 + 1) * 128 + p] + bperm[(layer * 8 + 3) * 128 + p]
            + bperm[(layer * 8 + 5) * 128 + p] + bperm[(layer * 8 + 7) * 128 + p];
    b0sum[layer * 128 + p] = s;
}

// ---------------- all-types fp32 -> bf16 convert (one launch) ----------------
__global__ void conv_all(const float* __restrict__ x0, const float* __restrict__ x1,
                         const float* __restrict__ x2, const float* __restrict__ x3,
                         const float* __restrict__ x4, u16* __restrict__ out, long n8type) {
    long i = (long)blockIdx.x * blockDim.x + threadIdx.x;
    if (i >= 5 * n8type) return;
    int t = (int)(i / n8type);
    long j = i - (long)t * n8type;
    const float* src = t == 0 ? x0 : t == 1 ? x1 : t == 2 ? x2 : t == 3 ? x3 : x4;
    float4 v0 = ((const float4*)src)[j * 2];
    float4 v1 = ((const float4*)src)[j * 2 + 1];
    union { u16 u[8]; uint4 q; } pk;
    pk.u[0] = f2bf(v0.x); pk.u[1] = f2bf(v0.y); pk.u[2] = f2bf(v0.z); pk.u[3] = f2bf(v0.w);
    pk.u[4] = f2bf(v1.x); pk.u[5] = f2bf(v1.y); pk.u[6] = f2bf(v1.z); pk.u[7] = f2bf(v1.w);
    ((uint4*)out)[i] = pk.q;
}

// ---------------- batched MFMA GEMM: all 8 relations (grid.y = r) ----------------
__global__ __launch_bounds__(256) void gemm_mfma(const u16* __restrict__ Xbf,
                                                 const u16* __restrict__ WfragL,
                                                 u16* __restrict__ Hs8,
                                                 float* __restrict__ es8,
                                                 float* __restrict__ ed8, int N) {
    const int r = blockIdx.y;
    const int stype = (r & 1) ? ((r >> 1) + 1) : 0;   // RS = {0,1,0,2,0,3,0,4}
    const u16* X  = Xbf + (size_t)stype * N * 128;
    const u16* Wf = WfragL + (size_t)r * 18432;
    u16*   Hs = Hs8 + (size_t)r * N * 128;
    float* es = es8 + (size_t)r * N * 4;
    float* ed = ed8 + (size_t)(r ^ 1) * N * 4;

    __shared__ u16 wlds[18432];
    const int tid = threadIdx.x;
    for (int i = tid; i < 2304; i += 256)
        ((s16x8*)wlds)[i] = ((const s16x8*)Wf)[i];

    const int wv = tid >> 6, l = tid & 63;
    const int lr = l & 15, lk = l >> 4;
    const int r0 = blockIdx.x * 128 + wv * 32;

    s16x8 af[2][4];
    #pragma unroll
    for (int rt = 0; rt < 2; ++rt) {
        int row = r0 + rt * 16 + lr;
        if (row > N - 1) row = N - 1;
        const s16x8* xp = (const s16x8*)(X + (size_t)row * 128 + lk * 8);
        af[rt][0] = xp[0]; af[rt][1] = xp[4]; af[rt][2] = xp[8]; af[rt][3] = xp[12];
    }
    __syncthreads();

    f32x4 acc[2][9] = {};
    #pragma unroll
    for (int ct = 0; ct < 9; ++ct) {
        s16x8 bf0 = ((s16x8*)wlds)[(ct * 4 + 0) * 64 + l];
        s16x8 bf1 = ((s16x8*)wlds)[(ct * 4 + 1) * 64 + l];
        s16x8 bf2 = ((s16x8*)wlds)[(ct * 4 + 2) * 64 + l];
        s16x8 bf3 = ((s16x8*)wlds)[(ct * 4 + 3) * 64 + l];
        #pragma unroll
        for (int rt = 0; rt < 2; ++rt) {
            acc[rt][ct] = __builtin_amdgcn_mfma_f32_16x16x32_bf16(af[rt][0], bf0, acc[rt][ct], 0, 0, 0);
            acc[rt][ct] = __builtin_amdgcn_mfma_f32_16x16x32_bf16(af[rt][1], bf1, acc[rt][ct], 0, 0, 0);
            acc[rt][ct] = __builtin_amdgcn_mfma_f32_16x16x32_bf16(af[rt][2], bf2, acc[rt][ct], 0, 0, 0);
            acc[rt][ct] = __builtin_amdgcn_mfma_f32_16x16x32_bf16(af[rt][3], bf3, acc[rt][ct], 0, 0, 0);
        }
    }

    #pragma unroll
    for (int rt = 0; rt < 2; ++rt) {
        #pragma unroll
        for (int j = 0; j < 4; ++j) {
            int row = r0 + rt * 16 + lk * 4 + j;
            if (row < N) {
                union { u16 u[8]; uint4 q; } pk;
                #pragma unroll
                for (int ct = 0; ct < 8; ++ct) pk.u[ct] = f2bf(acc[rt][ct][j]);
                *(uint4*)(Hs + (size_t)row * 128 + lr * 8) = pk.q;
                float evv = acc[rt][8][j];
                if (lr < 4)      es[(size_t)row * 4 + lr]     = evv;
                else if (lr < 8) ed[(size_t)row * 4 + lr - 4] = evv;
            }
        }
    }
}

// ---------------- CSR build (XCD-local: blockIdx%8 = relation) ----------------
__global__ void hist_kernel(const int* __restrict__ edges, int* __restrict__ counts,
                            int E, int N) {
    int r = blockIdx.x & 7;
    int e = (blockIdx.x >> 3) * 256 + threadIdx.x;
    if (e >= E) return;
    int d = edges[(size_t)r * 2 * E + E + e];
    atomicAdd(&counts[r * N + d], 1);
}

__global__ __launch_bounds__(256) void scan_block_k(const int* __restrict__ in,
                                                    int* __restrict__ outv,
                                                    int* __restrict__ bsum, int M) {
    __shared__ int sh[256];
    int t = threadIdx.x;
    int base = blockIdx.x * 2048 + t * 8;
    int vals[8];
    int tot = 0;
    #pragma unroll
    for (int j = 0; j < 8; ++j) {
        int v = (base + j < M) ? in[base + j] : 0;
        vals[j] = tot; tot += v;
    }
    sh[t] = tot;
    __syncthreads();
    for (int ofs = 1; ofs < 256; ofs <<= 1) {
        int y = 0;
        if (t >= ofs) y = sh[t - ofs];
        __syncthreads();
        if (t >= ofs) sh[t] += y;
        __syncthreads();
    }
    int ex = (t == 0) ? 0 : sh[t - 1];
    #pragma unroll
    for (int j = 0; j < 8; ++j)
        if (base + j < M) outv[base + j] = ex + vals[j];
    if (t == 255) bsum[blockIdx.x] = sh[255];
}

__global__ __launch_bounds__(1024) void scan_tops_k(const int* __restrict__ bsum,
                                                    int* __restrict__ bpref, int nb) {
    __shared__ int sh[1024];
    int t = threadIdx.x;
    int v = (t < nb) ? bsum[t] : 0;
    sh[t] = v;
    __syncthreads();
    for (int ofs = 1; ofs < 1024; ofs <<= 1) {
        int y = 0;
        if (t >= ofs) y = sh[t - ofs];
        __syncthreads();
        if (t >= ofs) sh[t] += y;
        __syncthreads();
    }
    if (t < nb) bpref[t] = sh[t] - v;
}

__global__ void scan_add_k(int* __restrict__ outv, const int* __restrict__ bpref, int M) {
    int g = blockIdx.x * blockDim.x + threadIdx.x;
    if (g < M) outv[g] += bpref[g >> 11];
}

__global__ void build_csr_k(const int* __restrict__ edges, int* __restrict__ pos,
                            int* __restrict__ srcs, int E, int N) {
    int r = blockIdx.x & 7;
    int e = (blockIdx.x >> 3) * 256 + threadIdx.x;
    if (e >= E) return;
    const int* b = edges + (size_t)r * 2 * E;
    int s = b[e], d = b[E + e];
    int idx = atomicAdd(&pos[r * N + d], 1);
    srcs[idx] = s;
}

// ---------------- pnorm: per-(dst,head) softmax -> normalized p, all 8 relations ----
__global__ __launch_bounds__(256) void pnorm_k(
        const int* __restrict__ srcsG, const int* __restrict__ offs,
        const int* __restrict__ counts, const float* __restrict__ es8,
        const float* __restrict__ ed8, float* __restrict__ pcsr, int N) {
    const int r = blockIdx.y;
    const int* OFF = offs + (size_t)r * N;
    const int* CNT = counts + (size_t)r * N;
    const float* ES = es8 + (size_t)r * N * 4;
    const float* ED = ed8 + (size_t)r * N * 4;
    int g = blockIdx.x * 256 + threadIdx.x;
    if (g >= N * 4) return;
    const int d = g >> 2, h = g & 3;
    const int o0 = OFF[d], dg = CNT[d];
    if (dg == 0) return;
    const float edv = ED[(size_t)d * 4 + h];
    float lc[8];
    float mx = -INFINITY;
    #pragma unroll
    for (int i = 0; i < 8; ++i) {
        if (i < dg) {
            int s = srcsG[o0 + i];
            float lv = ES[(size_t)s * 4 + h] + edv;
            lv = lv > 0.f ? lv : 0.2f * lv;
            lc[i] = lv;
            mx = fmaxf(mx, lv);
        }
    }
    for (int i = 8; i < dg; ++i) {
        int s = srcsG[o0 + i];
        float lv = ES[(size_t)s * 4 + h] + edv;
        lv = lv > 0.f ? lv : 0.2f * lv;
        mx = fmaxf(mx, lv);
    }
    float den = 0.f;
    #pragma unroll
    for (int i = 0; i < 8; ++i) {
        if (i < dg) { lc[i] = __expf(lc[i] - mx); den += lc[i]; }
    }
    for (int i = 8; i < dg; ++i) {
        int s = srcsG[o0 + i];
        float lv = ES[(size_t)s * 4 + h] + edv;
        lv = lv > 0.f ? lv : 0.2f * lv;
        den += __expf(lv - mx);
    }
    const float inv = 1.f / (den + 1e-16f);
    #pragma unroll
    for (int i = 0; i < 8; ++i) {
        if (i < dg) pcsr[(size_t)(o0 + i) * 4 + h] = lc[i] * inv;
    }
    for (int i = 8; i < dg; ++i) {
        int s = srcsG[o0 + i];
        float lv = ES[(size_t)s * 4 + h] + edv;
        lv = lv > 0.f ? lv : 0.2f * lv;
        pcsr[(size_t)(o0 + i) * 4 + h] = __expf(lv - mx) * inv;
    }
}

// ---------------- gather epilogue helper ----------------
// OUT_MODE 0: ELU -> bf16 perm layout. OUT_MODE 2: ELU fp32 un-permuted.
template<int OUT_MODE>
__device__ __forceinline__ void gather_epilogue(float* a, const float* bb, int ln,
                                                void* OP, size_t drow) {
    float4 b0 = *(const float4*)(bb + 8 * ln);
    float4 b1 = *(const float4*)(bb + 8 * ln + 4);
    a[0] += b0.x; a[1] += b0.y; a[2] += b0.z; a[3] += b0.w;
    a[4] += b1.x; a[5] += b1.y; a[6] += b1.z; a[7] += b1.w;
    if (OUT_MODE == 0) {
        union { u16 u[8]; uint4 q; } pk;
        #pragma unroll
        for (int j = 0; j < 8; ++j) pk.u[j] = f2bf(eluf(a[j]));
        *(uint4*)((u16*)OP + drow * 128 + 8 * ln) = pk.q;
    } else {
        float* o = (float*)OP + drow * 128;
        #pragma unroll
        for (int j = 0; j < 8; ++j)
            o[(j << 4) | ln] = eluf(a[j]);
    }
}

// ---------------- gather for dst type 0: 4 relations {1,3,5,7} in one pass ----------
template<int OUT_MODE>
__global__ __launch_bounds__(256) void gather_zero(
        const int* __restrict__ srcsG, const float* __restrict__ pcsr,
        const int* __restrict__ offs, const int* __restrict__ counts,
        const u16* __restrict__ Hs8, const float* __restrict__ b0sum,
        void* __restrict__ outBase, int N) {
    const int tid = threadIdx.x;
    const int ln  = tid & 15;
    const int d   = (blockIdx.x * 256 + tid) >> 4;
    const bool act = (d < N);
    const int dsafe = act ? d : 0;

    float a[8] = {};

    #pragma unroll
    for (int rr = 0; rr < 4; ++rr) {
        const int rel = 2 * rr + 1;
        const int* OFF = offs + (size_t)rel * N;
        const int* CNT = counts + (size_t)rel * N;
        const u16* HS  = Hs8 + (size_t)rel * N * 128;

        const int o0 = OFF[dsafe];
        const int dg = act ? CNT[dsafe] : 0;

        #pragma unroll
        for (int i = 0; i < 8; ++i) {
            if (i < dg) {
                int s = srcsG[o0 + i];
                float4 p4 = *(const float4*)(pcsr + (size_t)(o0 + i) * 4);
                uint4 hv  = *(const uint4*)(HS + (size_t)s * 128 + 8 * ln);
                a[0] += p4.x * bf2f((u16)(hv.x & 0xFFFF));
                a[1] += p4.x * bf2f((u16)(hv.x >> 16));
                a[2] += p4.y * bf2f((u16)(hv.y & 0xFFFF));
                a[3] += p4.y * bf2f((u16)(hv.y >> 16));
                a[4] += p4.z * bf2f((u16)(hv.z & 0xFFFF));
                a[5] += p4.z * bf2f((u16)(hv.z >> 16));
                a[6] += p4.w * bf2f((u16)(hv.w & 0xFFFF));
                a[7] += p4.w * bf2f((u16)(hv.w >> 16));
            }
        }
        for (int i = 8; i < dg; ++i) {
            int s = srcsG[o0 + i];
            float4 p4 = *(const float4*)(pcsr + (size_t)(o0 + i) * 4);
            uint4 hv  = *(const uint4*)(HS + (size_t)s * 128 + 8 * ln);
            a[0] += p4.x * bf2f((u16)(hv.x & 0xFFFF));
            a[1] += p4.x * bf2f((u16)(hv.x >> 16));
            a[2] += p4.y * bf2f((u16)(hv.y & 0xFFFF));
            a[3] += p4.y * bf2f((u16)(hv.y >> 16));
            a[4] += p4.z * bf2f((u16)(hv.z & 0xFFFF));
            a[5] += p4.z * bf2f((u16)(hv.z >> 16));
            a[6] += p4.w * bf2f((u16)(hv.w & 0xFFFF));
            a[7] += p4.w * bf2f((u16)(hv.w >> 16));
        }
    }
    if (!act) return;
    gather_epilogue<OUT_MODE>(a, b0sum, ln, outBase, (size_t)d);
}

// ---------------- gather for dst types 1..4 (grid.y = y, relation 2y) ----------------
template<int OUT_MODE>
__global__ __launch_bounds__(256) void gather_one(
        const int* __restrict__ srcsG, const float* __restrict__ pcsr,
        const int* __restrict__ offs, const int* __restrict__ counts,
        const u16* __restrict__ Hs8, const float* __restrict__ bpermL,
        void* __restrict__ outBase, int N) {
    const int y   = blockIdx.y;          // 0..3 -> relation 2y, dst type y+1
    const int rel = 2 * y;
    const int tid = threadIdx.x;
    const int ln  = tid & 15;
    const int d   = (blockIdx.x * 256 + tid) >> 4;
    const bool act = (d < N);
    const int dsafe = act ? d : 0;

    const int* OFF = offs + (size_t)rel * N;
    const int* CNT = counts + (size_t)rel * N;
    const u16* HS  = Hs8 + (size_t)rel * N * 128;

    float a[8] = {};
    const int o0 = OFF[dsafe];
    const int dg = act ? CNT[dsafe] : 0;

    #pragma unroll
    for (int i = 0; i < 8; ++i) {
        if (i < dg) {
            int s = srcsG[o0 + i];
            float4 p4 = *(const float4*)(pcsr + (size_t)(o0 + i) * 4);
            uint4 hv  = *(const uint4*)(HS + (size_t)s * 128 + 8 * ln);
            a[0] += p4.x * bf2f((u16)(hv.x & 0xFFFF));
            a[1] += p4.x * bf2f((u16)(hv.x >> 16));
            a[2] += p4.y * bf2f((u16)(hv.y & 0xFFFF));
            a[3] += p4.y * bf2f((u16)(hv.y >> 16));
            a[4] += p4.z * bf2f((u16)(hv.z & 0xFFFF));
            a[5] += p4.z * bf2f((u16)(hv.z >> 16));
            a[6] += p4.w * bf2f((u16)(hv.w & 0xFFFF));
            a[7] += p4.w * bf2f((u16)(hv.w >> 16));
        }
    }
    for (int i = 8; i < dg; ++i) {
        int s = srcsG[o0 + i];
        float4 p4 = *(const float4*)(pcsr + (size_t)(o0 + i) * 4);
        uint4 hv  = *(const uint4*)(HS + (size_t)s * 128 + 8 * ln);
        a[0] += p4.x * bf2f((u16)(hv.x & 0xFFFF));
        a[1] += p4.x * bf2f((u16)(hv.x >> 16));
        a[2] += p4.y * bf2f((u16)(hv.y & 0xFFFF));
        a[3] += p4.y * bf2f((u16)(hv.y >> 16));
        a[4] += p4.z * bf2f((u16)(hv.z & 0xFFFF));
        a[5] += p4.z * bf2f((u16)(hv.z >> 16));
        a[6] += p4.w * bf2f((u16)(hv.w & 0xFFFF));
        a[7] += p4.w * bf2f((u16)(hv.w >> 16));
    }
    if (!act) return;
    const float* bb = bpermL + (size_t)rel * 128;
    void* OP;
    if (OUT_MODE == 0) OP = (void*)((u16*)outBase + (size_t)(y + 1) * N * 128);
    else               OP = (void*)((float*)outBase + (size_t)(y + 1) * N * 128);
    gather_epilogue<OUT_MODE>(a, bb, ln, OP, (size_t)d);
}

extern "C" void kernel_launch(void* const* d_in, const int* in_sizes, int n_in,
                              void* d_out, int out_size, void* d_ws, size_t ws_size,
                              hipStream_t stream) {
    const int N = in_sizes[0] / 128;
    const int E = in_sizes[5] / (2 * NRELS);

    const float* xs0[5] = { (const float*)d_in[0], (const float*)d_in[1],
                            (const float*)d_in[2], (const float*)d_in[3],
                            (const float*)d_in[4] };
    const int*   edges = (const int*)d_in[5];
    const float* Ws1 = (const float*)d_in[6];
    const float* Wd1 = (const float*)d_in[7];
    const float* as1 = (const float*)d_in[8];
    const float* ad1 = (const float*)d_in[9];
    const float* b1  = (const float*)d_in[10];
    const float* Ws2 = (const float*)d_in[11];
    const float* Wd2 = (const float*)d_in[12];
    const float* as2 = (const float*)d_in[13];
    const float* ad2 = (const float*)d_in[14];
    const float* b2  = (const float*)d_in[15];
    float* out = (float*)d_out;

    // workspace layout (~417 MB; harness poison fills show ws_size ~1 GB)
    char* wp = (char*)d_ws;
    u16*   Xbf   = (u16*)wp;   wp += (size_t)5 * N * 128 * 2;
    u16*   Hs8   = (u16*)wp;   wp += (size_t)8 * N * 128 * 2;
    float* es8   = (float*)wp; wp += (size_t)8 * N * 4 * 4;
    float* ed8   = (float*)wp; wp += (size_t)8 * N * 4 * 4;
    float* pcsr  = (float*)wp; wp += (size_t)NRELS * E * 4 * 4;
    int* counts  = (int*)wp;   wp += (size_t)NRELS * N * 4;
    int* offs    = (int*)wp;   wp += (size_t)NRELS * N * 4;
    int* pos     = (int*)wp;   wp += (size_t)NRELS * N * 4;
    int* srcs    = (int*)wp;   wp += (size_t)NRELS * E * 4;
    u16* Wfrag   = (u16*)wp;   wp += (size_t)16 * 18432 * 2;
    float* bperm = (float*)wp; wp += (size_t)16 * 128 * 4;
    float* b0sum = (float*)wp; wp += (size_t)2 * 128 * 4;
    int* bsum    = (int*)wp;   wp += 1024 * 4;
    int* bpref   = (int*)wp;   wp += 1024 * 4;
    const size_t ws_used = (size_t)(wp - (char*)d_ws);
    if (ws_used > ws_size) return;

    // ---- re-establish the validated zero initial ws state on EVERY call ----
    hipMemsetAsync(d_ws, 0, ws_used, stream);

    // ---- weight prep ----
    prep_weights<<<dim3(16), 256, 0, stream>>>(Ws1, Wd1, as1, ad1, b1,
                                               Ws2, Wd2, as2, ad2, b2, Wfrag, bperm);
    prep_bsum<<<dim3(2), 128, 0, stream>>>(bperm, b0sum);

    // ---- build CSR (dst-sorted), XCD-local ----
    const int M  = NRELS * N;
    const int nb = (M + 2047) / 2048;
    const int eblocks = 8 * ((E + 255) / 256);
    hist_kernel<<<dim3(eblocks), 256, 0, stream>>>(edges, counts, E, N);
    scan_block_k<<<dim3(nb), 256, 0, stream>>>(counts, offs, bsum, M);
    scan_tops_k<<<dim3(1), 1024, 0, stream>>>(bsum, bpref, nb);
    scan_add_k<<<dim3((M + 255) / 256), 256, 0, stream>>>(offs, bpref, M);
    hipMemcpyAsync(pos, offs, (size_t)M * 4, hipMemcpyDeviceToDevice, stream);
    build_csr_k<<<dim3(eblocks), 256, 0, stream>>>(edges, pos, srcs, E, N);

    // ---- convert inputs to bf16 (single launch) ----
    const long n8type = (long)N * 128 / 8;
    conv_all<<<dim3((int)((5 * n8type + 255) / 256)), 256, 0, stream>>>(
        xs0[0], xs0[1], xs0[2], xs0[3], xs0[4], Xbf, n8type);

    const int gemmBlocks  = (N + 127) / 128;
    const int gBlocks     = (N + 15) / 16;   // 16 dsts per block
    const int pnormBlocks = (N * 4 + 255) / 256;

    for (int layer = 0; layer < 2; ++layer) {
        const u16*   WL = Wfrag + (size_t)layer * 8 * 18432;
        const float* bL = bperm + layer * 8 * 128;

        gemm_mfma<<<dim3(gemmBlocks, 8), 256, 0, stream>>>(Xbf, WL, Hs8, es8, ed8, N);
        pnorm_k<<<dim3(pnormBlocks, 8), 256, 0, stream>>>(
            srcs, offs, counts, es8, ed8, pcsr, N);
        if (layer == 0) {
            gather_zero<0><<<dim3(gBlocks), 256, 0, stream>>>(
                srcs, pcsr, offs, counts, Hs8, b0sum + 0 * 128, Xbf, N);
            gather_one<0><<<dim3(gBlocks, 4), 256, 0, stream>>>(
                srcs, pcsr, offs, counts, Hs8, bL, Xbf, N);
        } else {
            gather_zero<2><<<dim3(gBlocks), 256, 0, stream>>>(
                srcs, pcsr, offs, counts, Hs8, b0sum + 1 * 128, out, N);
            gather_one<2><<<dim3(gBlocks, 4), 256, 0, stream>>>(
                srcs, pcsr, offs, counts, Hs8, bL, out, N);
        }
    }
}

// Round 10
// 922.369 us; speedup vs baseline: 1.2150x; 1.2150x over previous
//
#include <hip/hip_runtime.h>

#define NRELS 8
typedef __attribute__((ext_vector_type(8))) short s16x8;
typedef __attribute__((ext_vector_type(4))) float f32x4;
typedef unsigned short u16;
typedef unsigned int u32;

__device__ __forceinline__ u16 f2bf(float v) {
    unsigned u = __float_as_uint(v);
    u += 0x7FFFu + ((u >> 16) & 1u);
    return (u16)(u >> 16);
}
__device__ __forceinline__ float bf2f(u16 h) {
    return __uint_as_float(((unsigned)h) << 16);
}
__device__ __forceinline__ float eluf(float x) { return x > 0.f ? x : __expf(x) - 1.f; }

// ---------------- weight prep (blocks 0..15) + b0sum (blocks 16,17) ----------------
__global__ void prep_weights(const float* __restrict__ Ws1, const float* __restrict__ Wd1,
                             const float* __restrict__ as1, const float* __restrict__ ad1,
                             const float* __restrict__ b1,
                             const float* __restrict__ Ws2, const float* __restrict__ Wd2,
                             const float* __restrict__ as2, const float* __restrict__ ad2,
                             const float* __restrict__ b2,
                             u16* __restrict__ Wfrag, float* __restrict__ bperm,
                             float* __restrict__ b0sum) {
    const int bid = blockIdx.x;
    if (bid >= 16) {
        const int layer = bid - 16;
        const float* bb = layer ? b2 : b1;
        if (threadIdx.x < 128) {
            int p = threadIdx.x;
            int oc = ((p & 7) << 4) | (p >> 3);
            b0sum[layer * 128 + p] = bb[1 * 128 + oc] + bb[3 * 128 + oc]
                                   + bb[5 * 128 + oc] + bb[7 * 128 + oc];
        }
        return;
    }
    const int layer = bid >> 3, r = bid & 7, r1 = r ^ 1;
    const float* Ws  = (layer ? Ws2 : Ws1) + (size_t)r  * 16384;
    const float* asp = (layer ? as2 : as1) + r  * 128;
    const float* Wdr = (layer ? Wd2 : Wd1) + (size_t)r1 * 16384;
    const float* adr = (layer ? ad2 : ad1) + r1 * 128;
    const float* bb  = (layer ? b2  : b1 ) + r  * 128;
    u16* wf = Wfrag + (size_t)bid * 18432;
    for (int f = threadIdx.x; f < 18432; f += blockDim.x) {
        int be   = f & 7;
        int lane = (f >> 3) & 63;
        int kc   = (f >> 9) & 3;
        int ct   = f >> 11;
        int k    = kc * 32 + (lane >> 4) * 8 + be;
        int krow = layer ? (((k & 7) << 4) | (k >> 3)) : k;
        int c    = lane & 15;
        float val;
        if (ct < 8) {
            val = Ws[(size_t)krow * 128 + ct * 16 + c];
        } else if (c < 4) {
            float s = 0.f;
            #pragma unroll
            for (int cc = 0; cc < 32; ++cc) s += Ws[(size_t)krow * 128 + c * 32 + cc] * asp[c * 32 + cc];
            val = s;
        } else if (c < 8) {
            int h = c - 4;
            float s = 0.f;
            #pragma unroll
            for (int cc = 0; cc < 32; ++cc) s += Wdr[(size_t)krow * 128 + h * 32 + cc] * adr[h * 32 + cc];
            val = s;
        } else {
            val = 0.f;
        }
        wf[f] = f2bf(val);
    }
    if (threadIdx.x < 128) {
        int p = threadIdx.x;
        bperm[bid * 128 + p] = bb[((p & 7) << 4) | (p >> 3)];
    }
}

// ---------------- MFMA GEMM: grid.y=6; y<2: type-0 src, 2 phases (rels y*4, y*4+2);
//                  y>=2: single relation 2(y-2)+1, src type y-1.
//                  FP32IN=1: read fp32 inputs directly (layer 1), else bf16 Xbf.
template<int FP32IN>
__global__ __launch_bounds__(256) void gemm_mfma(
        const float* __restrict__ x0, const float* __restrict__ x1,
        const float* __restrict__ x2, const float* __restrict__ x3,
        const float* __restrict__ x4,
        const u16* __restrict__ Xbf, const u16* __restrict__ WfragL,
        u16* __restrict__ Hs8, float* __restrict__ es8, float* __restrict__ ed8, int N) {
    __shared__ u16 wlds[18432];
    const int y = blockIdx.y;
    int rel0, nph, stype;
    if (y < 2) { rel0 = y * 4;         nph = 2; stype = 0; }
    else       { rel0 = 2 * (y - 2) + 1; nph = 1; stype = y - 1; }

    const int tid = threadIdx.x;
    const int wv = tid >> 6, l = tid & 63;
    const int lr = l & 15, lk = l >> 4;
    const int r0 = blockIdx.x * 128 + wv * 32;

    s16x8 af[2][4];
    if (FP32IN) {
        const float* Xf = stype == 0 ? x0 : stype == 1 ? x1 : stype == 2 ? x2
                        : stype == 3 ? x3 : x4;
        #pragma unroll
        for (int rt = 0; rt < 2; ++rt) {
            int row = r0 + rt * 16 + lr;
            if (row > N - 1) row = N - 1;
            const float* xp = Xf + (size_t)row * 128 + lk * 8;
            #pragma unroll
            for (int q = 0; q < 4; ++q) {
                float4 v0 = *(const float4*)(xp + q * 32);
                float4 v1 = *(const float4*)(xp + q * 32 + 4);
                s16x8 f;
                f[0] = (short)f2bf(v0.x); f[1] = (short)f2bf(v0.y);
                f[2] = (short)f2bf(v0.z); f[3] = (short)f2bf(v0.w);
                f[4] = (short)f2bf(v1.x); f[5] = (short)f2bf(v1.y);
                f[6] = (short)f2bf(v1.z); f[7] = (short)f2bf(v1.w);
                af[rt][q] = f;
            }
        }
    } else {
        const u16* X = Xbf + (size_t)stype * N * 128;
        #pragma unroll
        for (int rt = 0; rt < 2; ++rt) {
            int row = r0 + rt * 16 + lr;
            if (row > N - 1) row = N - 1;
            const s16x8* xp = (const s16x8*)(X + (size_t)row * 128 + lk * 8);
            af[rt][0] = xp[0]; af[rt][1] = xp[4]; af[rt][2] = xp[8]; af[rt][3] = xp[12];
        }
    }

    for (int ph = 0; ph < nph; ++ph) {
        const int r = rel0 + ph * 2;
        const u16* Wf = WfragL + (size_t)r * 18432;
        __syncthreads();
        for (int i = tid; i < 2304; i += 256)
            ((s16x8*)wlds)[i] = ((const s16x8*)Wf)[i];
        __syncthreads();

        f32x4 acc[2][9] = {};
        #pragma unroll
        for (int ct = 0; ct < 9; ++ct) {
            s16x8 bf0 = ((s16x8*)wlds)[(ct * 4 + 0) * 64 + l];
            s16x8 bf1 = ((s16x8*)wlds)[(ct * 4 + 1) * 64 + l];
            s16x8 bf2 = ((s16x8*)wlds)[(ct * 4 + 2) * 64 + l];
            s16x8 bf3 = ((s16x8*)wlds)[(ct * 4 + 3) * 64 + l];
            #pragma unroll
            for (int rt = 0; rt < 2; ++rt) {
                acc[rt][ct] = __builtin_amdgcn_mfma_f32_16x16x32_bf16(af[rt][0], bf0, acc[rt][ct], 0, 0, 0);
                acc[rt][ct] = __builtin_amdgcn_mfma_f32_16x16x32_bf16(af[rt][1], bf1, acc[rt][ct], 0, 0, 0);
                acc[rt][ct] = __builtin_amdgcn_mfma_f32_16x16x32_bf16(af[rt][2], bf2, acc[rt][ct], 0, 0, 0);
                acc[rt][ct] = __builtin_amdgcn_mfma_f32_16x16x32_bf16(af[rt][3], bf3, acc[rt][ct], 0, 0, 0);
            }
        }

        u16*   Hs = Hs8 + (size_t)r * N * 128;
        float* es = es8 + (size_t)r * N * 4;
        float* ed = ed8 + (size_t)(r ^ 1) * N * 4;
        #pragma unroll
        for (int rt = 0; rt < 2; ++rt) {
            #pragma unroll
            for (int j = 0; j < 4; ++j) {
                int row = r0 + rt * 16 + lk * 4 + j;
                if (row < N) {
                    union { u16 u[8]; uint4 q; } pk;
                    #pragma unroll
                    for (int ct = 0; ct < 8; ++ct) pk.u[ct] = f2bf(acc[rt][ct][j]);
                    *(uint4*)(Hs + (size_t)row * 128 + lr * 8) = pk.q;
                    float evv = acc[rt][8][j];
                    if (lr < 4)      es[(size_t)row * 4 + lr]     = evv;
                    else if (lr < 8) ed[(size_t)row * 4 + lr - 4] = evv;
                }
            }
        }
    }
}

// ---------------- CSR build (XCD-local: blockIdx%8 = relation) ----------------
__global__ void hist_kernel(const int* __restrict__ edges, int* __restrict__ counts,
                            int E, int N) {
    int r = blockIdx.x & 7;
    int e = (blockIdx.x >> 3) * 256 + threadIdx.x;
    if (e >= E) return;
    int d = edges[(size_t)r * 2 * E + E + e];
    atomicAdd(&counts[r * N + d], 1);
}

__global__ __launch_bounds__(256) void scan_block_k(const int* __restrict__ in,
                                                    int* __restrict__ outv,
                                                    int* __restrict__ bsum, int M) {
    __shared__ int sh[256];
    int t = threadIdx.x;
    int base = blockIdx.x * 2048 + t * 8;
    int vals[8];
    int tot = 0;
    #pragma unroll
    for (int j = 0; j < 8; ++j) {
        int v = (base + j < M) ? in[base + j] : 0;
        vals[j] = tot; tot += v;
    }
    sh[t] = tot;
    __syncthreads();
    for (int ofs = 1; ofs < 256; ofs <<= 1) {
        int y = 0;
        if (t >= ofs) y = sh[t - ofs];
        __syncthreads();
        if (t >= ofs) sh[t] += y;
        __syncthreads();
    }
    int ex = (t == 0) ? 0 : sh[t - 1];
    #pragma unroll
    for (int j = 0; j < 8; ++j)
        if (base + j < M) outv[base + j] = ex + vals[j];
    if (t == 255) bsum[blockIdx.x] = sh[255];
}

__global__ __launch_bounds__(1024) void scan_tops_k(const int* __restrict__ bsum,
                                                    int* __restrict__ bpref, int nb) {
    __shared__ int sh[1024];
    int t = threadIdx.x;
    int v = (t < nb) ? bsum[t] : 0;
    sh[t] = v;
    __syncthreads();
    for (int ofs = 1; ofs < 1024; ofs <<= 1) {
        int y = 0;
        if (t >= ofs) y = sh[t - ofs];
        __syncthreads();
        if (t >= ofs) sh[t] += y;
        __syncthreads();
    }
    if (t < nb) bpref[t] = sh[t] - v;
}

// adds block prefix; writes BOTH offs (final) and pos (working copy for build)
__global__ void scan_add_k(int* __restrict__ outv, int* __restrict__ pos,
                           const int* __restrict__ bpref, int M) {
    int g = blockIdx.x * blockDim.x + threadIdx.x;
    if (g < M) {
        int v = outv[g] + bpref[g >> 11];
        outv[g] = v;
        pos[g] = v;
    }
}

__global__ void build_csr_k(const int* __restrict__ edges, int* __restrict__ pos,
                            int* __restrict__ srcs, int E, int N) {
    int r = blockIdx.x & 7;
    int e = (blockIdx.x >> 3) * 256 + threadIdx.x;
    if (e >= E) return;
    const int* b = edges + (size_t)r * 2 * E;
    int s = b[e], d = b[E + e];
    int idx = atomicAdd(&pos[r * N + d], 1);
    srcs[idx] = s;
}

// ---------------- pnorm: per-(dst,head) softmax -> normalized p, all 8 relations ----
__global__ __launch_bounds__(256) void pnorm_k(
        const int* __restrict__ srcsG, const int* __restrict__ offs,
        const int* __restrict__ counts, const float* __restrict__ es8,
        const float* __restrict__ ed8, float* __restrict__ pcsr, int N) {
    const int r = blockIdx.y;
    const int* OFF = offs + (size_t)r * N;
    const int* CNT = counts + (size_t)r * N;
    const float* ES = es8 + (size_t)r * N * 4;
    const float* ED = ed8 + (size_t)r * N * 4;
    int g = blockIdx.x * 256 + threadIdx.x;
    if (g >= N * 4) return;
    const int d = g >> 2, h = g & 3;
    const int o0 = OFF[d], dg = CNT[d];
    if (dg == 0) return;
    const float edv = ED[(size_t)d * 4 + h];
    float lc[8];
    float mx = -INFINITY;
    #pragma unroll
    for (int i = 0; i < 8; ++i) {
        if (i < dg) {
            int s = srcsG[o0 + i];
            float lv = ES[(size_t)s * 4 + h] + edv;
            lv = lv > 0.f ? lv : 0.2f * lv;
            lc[i] = lv;
            mx = fmaxf(mx, lv);
        }
    }
    for (int i = 8; i < dg; ++i) {
        int s = srcsG[o0 + i];
        float lv = ES[(size_t)s * 4 + h] + edv;
        lv = lv > 0.f ? lv : 0.2f * lv;
        mx = fmaxf(mx, lv);
    }
    float den = 0.f;
    #pragma unroll
    for (int i = 0; i < 8; ++i) {
        if (i < dg) { lc[i] = __expf(lc[i] - mx); den += lc[i]; }
    }
    for (int i = 8; i < dg; ++i) {
        int s = srcsG[o0 + i];
        float lv = ES[(size_t)s * 4 + h] + edv;
        lv = lv > 0.f ? lv : 0.2f * lv;
        den += __expf(lv - mx);
    }
    const float inv = 1.f / (den + 1e-16f);
    #pragma unroll
    for (int i = 0; i < 8; ++i) {
        if (i < dg) pcsr[(size_t)(o0 + i) * 4 + h] = lc[i] * inv;
    }
    for (int i = 8; i < dg; ++i) {
        int s = srcsG[o0 + i];
        float lv = ES[(size_t)s * 4 + h] + edv;
        lv = lv > 0.f ? lv : 0.2f * lv;
        pcsr[(size_t)(o0 + i) * 4 + h] = __expf(lv - mx) * inv;
    }
}

// ---------------- gather accumulate for one relation (branchless first 4 edges) -----
__device__ __forceinline__ void acc_rel(float a[8], const int* __restrict__ srcsG,
        const float* __restrict__ pcsr, const int* __restrict__ OFF,
        const int* __restrict__ CNT, const u16* __restrict__ HS,
        int ds, bool act, int ln) {
    const int o0 = OFF[ds];
    const int dg = act ? CNT[ds] : 0;
    if (dg == 0) return;
    #pragma unroll
    for (int i = 0; i < 4; ++i) {
        int idx = o0 + (i < dg ? i : dg - 1);
        int s = srcsG[idx];
        float4 p4 = *(const float4*)(pcsr + (size_t)idx * 4);
        uint4 hv  = *(const uint4*)(HS + (size_t)s * 128 + 8 * ln);
        if (i >= dg) { p4.x = 0.f; p4.y = 0.f; p4.z = 0.f; p4.w = 0.f; }
        a[0] += p4.x * bf2f((u16)(hv.x & 0xFFFF)); a[1] += p4.x * bf2f((u16)(hv.x >> 16));
        a[2] += p4.y * bf2f((u16)(hv.y & 0xFFFF)); a[3] += p4.y * bf2f((u16)(hv.y >> 16));
        a[4] += p4.z * bf2f((u16)(hv.z & 0xFFFF)); a[5] += p4.z * bf2f((u16)(hv.z >> 16));
        a[6] += p4.w * bf2f((u16)(hv.w & 0xFFFF)); a[7] += p4.w * bf2f((u16)(hv.w >> 16));
    }
    #pragma unroll
    for (int i = 4; i < 8; ++i) {
        if (i < dg) {
            int idx = o0 + i;
            int s = srcsG[idx];
            float4 p4 = *(const float4*)(pcsr + (size_t)idx * 4);
            uint4 hv  = *(const uint4*)(HS + (size_t)s * 128 + 8 * ln);
            a[0] += p4.x * bf2f((u16)(hv.x & 0xFFFF)); a[1] += p4.x * bf2f((u16)(hv.x >> 16));
            a[2] += p4.y * bf2f((u16)(hv.y & 0xFFFF)); a[3] += p4.y * bf2f((u16)(hv.y >> 16));
            a[4] += p4.z * bf2f((u16)(hv.z & 0xFFFF)); a[5] += p4.z * bf2f((u16)(hv.z >> 16));
            a[6] += p4.w * bf2f((u16)(hv.w & 0xFFFF)); a[7] += p4.w * bf2f((u16)(hv.w >> 16));
        }
    }
    for (int i = 8; i < dg; ++i) {
        int idx = o0 + i;
        int s = srcsG[idx];
        float4 p4 = *(const float4*)(pcsr + (size_t)idx * 4);
        uint4 hv  = *(const uint4*)(HS + (size_t)s * 128 + 8 * ln);
        a[0] += p4.x * bf2f((u16)(hv.x & 0xFFFF)); a[1] += p4.x * bf2f((u16)(hv.x >> 16));
        a[2] += p4.y * bf2f((u16)(hv.y & 0xFFFF)); a[3] += p4.y * bf2f((u16)(hv.y >> 16));
        a[4] += p4.z * bf2f((u16)(hv.z & 0xFFFF)); a[5] += p4.z * bf2f((u16)(hv.z >> 16));
        a[6] += p4.w * bf2f((u16)(hv.w & 0xFFFF)); a[7] += p4.w * bf2f((u16)(hv.w >> 16));
    }
}

// ---------------- merged gather: grid.y=0 -> dst type 0 (rels 1,3,5,7);
//                  grid.y=1..4 -> dst type y (rel 2(y-1)).
// OUT_MODE 0: ELU->bf16 perm layout (Xbf). OUT_MODE 2: ELU fp32 un-permuted (d_out).
template<int OUT_MODE>
__global__ __launch_bounds__(256) void gat_all(
        const int* __restrict__ srcsG, const float* __restrict__ pcsr,
        const int* __restrict__ offs, const int* __restrict__ counts,
        const u16* __restrict__ Hs8, const float* __restrict__ bpermL,
        const float* __restrict__ b0sumL, void* __restrict__ outBase, int N) {
    const int y   = blockIdx.y;
    const int tid = threadIdx.x;
    const int ln  = tid & 15;
    const int d   = (blockIdx.x * 256 + tid) >> 4;
    const bool act = (d < N);
    const int ds = act ? d : 0;

    float a[8] = {};
    const float* bb;
    size_t slice;
    if (y == 0) {
        #pragma unroll
        for (int rr = 0; rr < 4; ++rr) {
            const int rel = 2 * rr + 1;
            acc_rel(a, srcsG, pcsr, offs + (size_t)rel * N, counts + (size_t)rel * N,
                    Hs8 + (size_t)rel * N * 128, ds, act, ln);
        }
        bb = b0sumL;
        slice = 0;
    } else {
        const int rel = 2 * (y - 1);
        acc_rel(a, srcsG, pcsr, offs + (size_t)rel * N, counts + (size_t)rel * N,
                Hs8 + (size_t)rel * N * 128, ds, act, ln);
        bb = bpermL + (size_t)rel * 128;
        slice = (size_t)y * N * 128;
    }
    if (!act) return;

    float4 b0 = *(const float4*)(bb + 8 * ln);
    float4 b1 = *(const float4*)(bb + 8 * ln + 4);
    a[0] += b0.x; a[1] += b0.y; a[2] += b0.z; a[3] += b0.w;
    a[4] += b1.x; a[5] += b1.y; a[6] += b1.z; a[7] += b1.w;

    if (OUT_MODE == 0) {
        u16* OP = (u16*)outBase + slice;
        union { u16 u[8]; uint4 q; } pk;
        #pragma unroll
        for (int j = 0; j < 8; ++j) pk.u[j] = f2bf(eluf(a[j]));
        *(uint4*)(OP + (size_t)d * 128 + 8 * ln) = pk.q;
    } else {
        float* OP = (float*)outBase + slice;
        float* o = OP + (size_t)d * 128;
        #pragma unroll
        for (int j = 0; j < 8; ++j)
            o[(j << 4) | ln] = eluf(a[j]);
    }
}

extern "C" void kernel_launch(void* const* d_in, const int* in_sizes, int n_in,
                              void* d_out, int out_size, void* d_ws, size_t ws_size,
                              hipStream_t stream) {
    const int N = in_sizes[0] / 128;
    const int E = in_sizes[5] / (2 * NRELS);

    const float* xs0[5] = { (const float*)d_in[0], (const float*)d_in[1],
                            (const float*)d_in[2], (const float*)d_in[3],
                            (const float*)d_in[4] };
    const int*   edges = (const int*)d_in[5];
    const float* Ws1 = (const float*)d_in[6];
    const float* Wd1 = (const float*)d_in[7];
    const float* as1 = (const float*)d_in[8];
    const float* ad1 = (const float*)d_in[9];
    const float* b1  = (const float*)d_in[10];
    const float* Ws2 = (const float*)d_in[11];
    const float* Wd2 = (const float*)d_in[12];
    const float* as2 = (const float*)d_in[13];
    const float* ad2 = (const float*)d_in[14];
    const float* b2  = (const float*)d_in[15];
    float* out = (float*)d_out;

    // workspace layout (~417 MB; ws_size ~1 GB)
    char* wp = (char*)d_ws;
    u16*   Xbf   = (u16*)wp;   wp += (size_t)5 * N * 128 * 2;
    u16*   Hs8   = (u16*)wp;   wp += (size_t)8 * N * 128 * 2;
    float* es8   = (float*)wp; wp += (size_t)8 * N * 4 * 4;
    float* ed8   = (float*)wp; wp += (size_t)8 * N * 4 * 4;
    float* pcsr  = (float*)wp; wp += (size_t)NRELS * E * 4 * 4;
    int* counts  = (int*)wp;   wp += (size_t)NRELS * N * 4;
    int* offs    = (int*)wp;   wp += (size_t)NRELS * N * 4;
    int* pos     = (int*)wp;   wp += (size_t)NRELS * N * 4;
    int* srcs    = (int*)wp;   wp += (size_t)NRELS * E * 4;
    u16* Wfrag   = (u16*)wp;   wp += (size_t)16 * 18432 * 2;
    float* bperm = (float*)wp; wp += (size_t)16 * 128 * 4;
    float* b0sum = (float*)wp; wp += (size_t)2 * 128 * 4;
    int* bsum    = (int*)wp;   wp += 1024 * 4;
    int* bpref   = (int*)wp;   wp += 1024 * 4;
    const size_t ws_used = (size_t)(wp - (char*)d_ws);
    if (ws_used > ws_size) return;

    // ---- zero ONLY the atomic histogram (full write-before-read audit: every other
    //      ws buffer is fully written earlier in the same call than it is read) ----
    const int M = NRELS * N;
    hipMemsetAsync(counts, 0, (size_t)M * 4, stream);

    // ---- weight prep (+ b0sum) ----
    prep_weights<<<dim3(18), 256, 0, stream>>>(Ws1, Wd1, as1, ad1, b1,
                                               Ws2, Wd2, as2, ad2, b2,
                                               Wfrag, bperm, b0sum);

    // ---- build CSR (dst-sorted), XCD-local ----
    const int nb = (M + 2047) / 2048;
    const int eblocks = 8 * ((E + 255) / 256);
    hist_kernel<<<dim3(eblocks), 256, 0, stream>>>(edges, counts, E, N);
    scan_block_k<<<dim3(nb), 256, 0, stream>>>(counts, offs, bsum, M);
    scan_tops_k<<<dim3(1), 1024, 0, stream>>>(bsum, bpref, nb);
    scan_add_k<<<dim3((M + 255) / 256), 256, 0, stream>>>(offs, pos, bpref, M);
    build_csr_k<<<dim3(eblocks), 256, 0, stream>>>(edges, pos, srcs, E, N);

    const int gemmBlocks  = (N + 127) / 128;
    const int gBlocks     = (N + 15) / 16;
    const int pnormBlocks = (N * 4 + 255) / 256;

    for (int layer = 0; layer < 2; ++layer) {
        const u16*   WL = Wfrag + (size_t)layer * 8 * 18432;
        const float* bL = bperm + layer * 8 * 128;

        if (layer == 0)
            gemm_mfma<1><<<dim3(gemmBlocks, 6), 256, 0, stream>>>(
                xs0[0], xs0[1], xs0[2], xs0[3], xs0[4], nullptr, WL, Hs8, es8, ed8, N);
        else
            gemm_mfma<0><<<dim3(gemmBlocks, 6), 256, 0, stream>>>(
                nullptr, nullptr, nullptr, nullptr, nullptr, Xbf, WL, Hs8, es8, ed8, N);

        pnorm_k<<<dim3(pnormBlocks, 8), 256, 0, stream>>>(
            srcs, offs, counts, es8, ed8, pcsr, N);

        if (layer == 0)
            gat_all<0><<<dim3(gBlocks, 5), 256, 0, stream>>>(
                srcs, pcsr, offs, counts, Hs8, bL, b0sum + 0 * 128, Xbf, N);
        else
            gat_all<2><<<dim3(gBlocks, 5), 256, 0, stream>>>(
                srcs, pcsr, offs, counts, Hs8, bL, b0sum + 1 * 128, out, N);
    }
}

// Round 11
// 860.342 us; speedup vs baseline: 1.3026x; 1.0721x over previous
//
#include <hip/hip_runtime.h>

#define NRELS 8
typedef __attribute__((ext_vector_type(8))) short s16x8;
typedef __attribute__((ext_vector_type(4))) float f32x4;
typedef unsigned short u16;
typedef unsigned int u32;

__device__ __forceinline__ u16 f2bf(float v) {
    unsigned u = __float_as_uint(v);
    u += 0x7FFFu + ((u >> 16) & 1u);
    return (u16)(u >> 16);
}
__device__ __forceinline__ float bf2f(u16 h) {
    return __uint_as_float(((unsigned)h) << 16);
}
__device__ __forceinline__ float eluf(float x) { return x > 0.f ? x : __expf(x) - 1.f; }

// ---------------- prep (blocks 0..15) + b0sum (16,17) + hist (18..) ----------------
__global__ void prep_hist(const float* __restrict__ Ws1, const float* __restrict__ Wd1,
                          const float* __restrict__ as1, const float* __restrict__ ad1,
                          const float* __restrict__ b1,
                          const float* __restrict__ Ws2, const float* __restrict__ Wd2,
                          const float* __restrict__ as2, const float* __restrict__ ad2,
                          const float* __restrict__ b2,
                          u16* __restrict__ Wfrag, float* __restrict__ bperm,
                          float* __restrict__ b0sum,
                          const int* __restrict__ edges, int* __restrict__ counts,
                          int E, int N) {
    const int bid = blockIdx.x;
    if (bid >= 18) {
        const int hb = bid - 18;
        const int r = hb & 7;
        const int e = (hb >> 3) * 256 + threadIdx.x;
        if (e >= E) return;
        int d = edges[(size_t)r * 2 * E + E + e];
        atomicAdd(&counts[r * N + d], 1);
        return;
    }
    if (bid >= 16) {
        const int layer = bid - 16;
        const float* bb = layer ? b2 : b1;
        if (threadIdx.x < 128) {
            int p = threadIdx.x;
            int oc = ((p & 7) << 4) | (p >> 3);
            b0sum[layer * 128 + p] = bb[1 * 128 + oc] + bb[3 * 128 + oc]
                                   + bb[5 * 128 + oc] + bb[7 * 128 + oc];
        }
        return;
    }
    const int layer = bid >> 3, r = bid & 7, r1 = r ^ 1;
    const float* Ws  = (layer ? Ws2 : Ws1) + (size_t)r  * 16384;
    const float* asp = (layer ? as2 : as1) + r  * 128;
    const float* Wdr = (layer ? Wd2 : Wd1) + (size_t)r1 * 16384;
    const float* adr = (layer ? ad2 : ad1) + r1 * 128;
    const float* bb  = (layer ? b2  : b1 ) + r  * 128;
    u16* wf = Wfrag + (size_t)bid * 18432;
    for (int f = threadIdx.x; f < 18432; f += blockDim.x) {
        int be   = f & 7;
        int lane = (f >> 3) & 63;
        int kc   = (f >> 9) & 3;
        int ct   = f >> 11;
        int k    = kc * 32 + (lane >> 4) * 8 + be;
        int krow = layer ? (((k & 7) << 4) | (k >> 3)) : k;
        int c    = lane & 15;
        float val;
        if (ct < 8) {
            val = Ws[(size_t)krow * 128 + ct * 16 + c];
        } else if (c < 4) {
            float s = 0.f;
            #pragma unroll
            for (int cc = 0; cc < 32; ++cc) s += Ws[(size_t)krow * 128 + c * 32 + cc] * asp[c * 32 + cc];
            val = s;
        } else if (c < 8) {
            int h = c - 4;
            float s = 0.f;
            #pragma unroll
            for (int cc = 0; cc < 32; ++cc) s += Wdr[(size_t)krow * 128 + h * 32 + cc] * adr[h * 32 + cc];
            val = s;
        } else {
            val = 0.f;
        }
        wf[f] = f2bf(val);
    }
    if (threadIdx.x < 128) {
        int p = threadIdx.x;
        bperm[bid * 128 + p] = bb[((p & 7) << 4) | (p >> 3)];
    }
}

// ---------------- shared gemm inner body (phases over relations rel0, rel0+2, ...) ----
__device__ __forceinline__ void gemm_phases(const s16x8 af[2][4], u16* wlds,
        const u16* __restrict__ WfragL, int rel0, int nph,
        u16* __restrict__ Hs8, float* __restrict__ es8, float* __restrict__ ed8,
        int r0, int N, int tid) {
    const int l = tid & 63, lr = l & 15, lk = l >> 4;
    for (int ph = 0; ph < nph; ++ph) {
        const int r = rel0 + ph * 2;
        const u16* Wf = WfragL + (size_t)r * 18432;
        __syncthreads();
        for (int i = tid; i < 2304; i += 256)
            ((s16x8*)wlds)[i] = ((const s16x8*)Wf)[i];
        __syncthreads();

        f32x4 acc[2][9] = {};
        #pragma unroll
        for (int ct = 0; ct < 9; ++ct) {
            s16x8 bf0 = ((s16x8*)wlds)[(ct * 4 + 0) * 64 + l];
            s16x8 bf1 = ((s16x8*)wlds)[(ct * 4 + 1) * 64 + l];
            s16x8 bf2 = ((s16x8*)wlds)[(ct * 4 + 2) * 64 + l];
            s16x8 bf3 = ((s16x8*)wlds)[(ct * 4 + 3) * 64 + l];
            #pragma unroll
            for (int rt = 0; rt < 2; ++rt) {
                acc[rt][ct] = __builtin_amdgcn_mfma_f32_16x16x32_bf16(af[rt][0], bf0, acc[rt][ct], 0, 0, 0);
                acc[rt][ct] = __builtin_amdgcn_mfma_f32_16x16x32_bf16(af[rt][1], bf1, acc[rt][ct], 0, 0, 0);
                acc[rt][ct] = __builtin_amdgcn_mfma_f32_16x16x32_bf16(af[rt][2], bf2, acc[rt][ct], 0, 0, 0);
                acc[rt][ct] = __builtin_amdgcn_mfma_f32_16x16x32_bf16(af[rt][3], bf3, acc[rt][ct], 0, 0, 0);
            }
        }

        u16*   Hs = Hs8 + (size_t)r * N * 128;
        float* es = es8 + (size_t)r * N * 4;
        float* ed = ed8 + (size_t)(r ^ 1) * N * 4;
        #pragma unroll
        for (int rt = 0; rt < 2; ++rt) {
            #pragma unroll
            for (int j = 0; j < 4; ++j) {
                int row = r0 + rt * 16 + lk * 4 + j;
                if (row < N) {
                    union { u16 u[8]; uint4 q; } pk;
                    #pragma unroll
                    for (int ct = 0; ct < 8; ++ct) pk.u[ct] = f2bf(acc[rt][ct][j]);
                    *(uint4*)(Hs + (size_t)row * 128 + lr * 8) = pk.q;
                    float evv = acc[rt][8][j];
                    if (lr < 4)      es[(size_t)row * 4 + lr]     = evv;
                    else if (lr < 8) ed[(size_t)row * 4 + lr - 4] = evv;
                }
            }
        }
    }
}

__device__ __forceinline__ void ymap(int y, int& rel0, int& nph, int& stype) {
    if (y < 2) { rel0 = y * 4;           nph = 2; stype = 0; }
    else       { rel0 = 2 * (y - 2) + 1; nph = 1; stype = y - 1; }
}

// ---------------- fused: layer-1 gemm (fp32 in) INTERLEAVED with CSR build ----------
// block bx: bx%3==0 -> gemm slot q=bx/3 (q<gemmBlocks*6); else build slot bi=bx-bx/3-1.
__global__ __launch_bounds__(256) void gemm1_build(
        const float* __restrict__ x0, const float* __restrict__ x1,
        const float* __restrict__ x2, const float* __restrict__ x3,
        const float* __restrict__ x4,
        const u16* __restrict__ WfragL,
        u16* __restrict__ Hs8, float* __restrict__ es8, float* __restrict__ ed8,
        const int* __restrict__ edges, int* __restrict__ pos, int* __restrict__ srcs,
        int gemmBlocks, int E, int N) {
    __shared__ u16 wlds[18432];
    const int bx = blockIdx.x;
    const int q = bx / 3, rm = bx % 3;
    const int tid = threadIdx.x;

    if (rm != 0) {
        // ---- CSR build path ----
        const int bi = bx - q - 1;
        const int nEB = (E + 255) / 256;
        if (bi >= 8 * nEB) return;
        const int rel = bi & 7;
        const int e = (bi >> 3) * 256 + tid;
        if (e >= E) return;
        const int* b = edges + (size_t)rel * 2 * E;
        int s = b[e], d = b[E + e];
        int idx = atomicAdd(&pos[rel * N + d], 1);
        srcs[idx] = s;
        return;
    }
    // ---- gemm path (layer 1, fp32 inputs) ----
    if (q >= gemmBlocks * 6) return;
    const int gx = q % gemmBlocks;
    const int y  = q / gemmBlocks;
    int rel0, nph, stype;
    ymap(y, rel0, nph, stype);

    const int l = tid & 63, lr = l & 15, lk = l >> 4;
    const int wv = tid >> 6;
    const int r0 = gx * 128 + wv * 32;

    const float* Xf = stype == 0 ? x0 : stype == 1 ? x1 : stype == 2 ? x2
                    : stype == 3 ? x3 : x4;
    s16x8 af[2][4];
    #pragma unroll
    for (int rt = 0; rt < 2; ++rt) {
        int row = r0 + rt * 16 + lr;
        if (row > N - 1) row = N - 1;
        const float* xp = Xf + (size_t)row * 128 + lk * 8;
        #pragma unroll
        for (int qq = 0; qq < 4; ++qq) {
            float4 v0 = *(const float4*)(xp + qq * 32);
            float4 v1 = *(const float4*)(xp + qq * 32 + 4);
            s16x8 f;
            f[0] = (short)f2bf(v0.x); f[1] = (short)f2bf(v0.y);
            f[2] = (short)f2bf(v0.z); f[3] = (short)f2bf(v0.w);
            f[4] = (short)f2bf(v1.x); f[5] = (short)f2bf(v1.y);
            f[6] = (short)f2bf(v1.z); f[7] = (short)f2bf(v1.w);
            af[rt][qq] = f;
        }
    }
    gemm_phases(af, wlds, WfragL, rel0, nph, Hs8, es8, ed8, r0, N, tid);
}

// ---------------- layer-2 gemm (bf16 Xbf inputs), grid.y = 6 ----------------
__global__ __launch_bounds__(256) void gemm2_mfma(
        const u16* __restrict__ Xbf, const u16* __restrict__ WfragL,
        u16* __restrict__ Hs8, float* __restrict__ es8, float* __restrict__ ed8, int N) {
    __shared__ u16 wlds[18432];
    const int tid = threadIdx.x;
    int rel0, nph, stype;
    ymap(blockIdx.y, rel0, nph, stype);
    const int l = tid & 63, lr = l & 15, lk = l >> 4;
    const int wv = tid >> 6;
    const int r0 = blockIdx.x * 128 + wv * 32;

    const u16* X = Xbf + (size_t)stype * N * 128;
    s16x8 af[2][4];
    #pragma unroll
    for (int rt = 0; rt < 2; ++rt) {
        int row = r0 + rt * 16 + lr;
        if (row > N - 1) row = N - 1;
        const s16x8* xp = (const s16x8*)(X + (size_t)row * 128 + lk * 8);
        af[rt][0] = xp[0]; af[rt][1] = xp[4]; af[rt][2] = xp[8]; af[rt][3] = xp[12];
    }
    gemm_phases(af, wlds, WfragL, rel0, nph, Hs8, es8, ed8, r0, N, tid);
}

// ---------------- scan chain ----------------
__global__ __launch_bounds__(256) void scan_block_k(const int* __restrict__ in,
                                                    int* __restrict__ outv,
                                                    int* __restrict__ bsum, int M) {
    __shared__ int sh[256];
    int t = threadIdx.x;
    int base = blockIdx.x * 2048 + t * 8;
    int vals[8];
    int tot = 0;
    #pragma unroll
    for (int j = 0; j < 8; ++j) {
        int v = (base + j < M) ? in[base + j] : 0;
        vals[j] = tot; tot += v;
    }
    sh[t] = tot;
    __syncthreads();
    for (int ofs = 1; ofs < 256; ofs <<= 1) {
        int y = 0;
        if (t >= ofs) y = sh[t - ofs];
        __syncthreads();
        if (t >= ofs) sh[t] += y;
        __syncthreads();
    }
    int ex = (t == 0) ? 0 : sh[t - 1];
    #pragma unroll
    for (int j = 0; j < 8; ++j)
        if (base + j < M) outv[base + j] = ex + vals[j];
    if (t == 255) bsum[blockIdx.x] = sh[255];
}

__global__ __launch_bounds__(1024) void scan_tops_k(const int* __restrict__ bsum,
                                                    int* __restrict__ bpref, int nb) {
    __shared__ int sh[1024];
    int t = threadIdx.x;
    int v = (t < nb) ? bsum[t] : 0;
    sh[t] = v;
    __syncthreads();
    for (int ofs = 1; ofs < 1024; ofs <<= 1) {
        int y = 0;
        if (t >= ofs) y = sh[t - ofs];
        __syncthreads();
        if (t >= ofs) sh[t] += y;
        __syncthreads();
    }
    if (t < nb) bpref[t] = sh[t] - v;
}

__global__ void scan_add_k(int* __restrict__ outv, int* __restrict__ pos,
                           const int* __restrict__ bpref, int M) {
    int g = blockIdx.x * blockDim.x + threadIdx.x;
    if (g < M) {
        int v = outv[g] + bpref[g >> 11];
        outv[g] = v;
        pos[g] = v;
    }
}

// ---------------- pnorm ----------------
__global__ __launch_bounds__(256) void pnorm_k(
        const int* __restrict__ srcsG, const int* __restrict__ offs,
        const int* __restrict__ counts, const float* __restrict__ es8,
        const float* __restrict__ ed8, float* __restrict__ pcsr, int N) {
    const int r = blockIdx.y;
    const int* OFF = offs + (size_t)r * N;
    const int* CNT = counts + (size_t)r * N;
    const float* ES = es8 + (size_t)r * N * 4;
    const float* ED = ed8 + (size_t)r * N * 4;
    int g = blockIdx.x * 256 + threadIdx.x;
    if (g >= N * 4) return;
    const int d = g >> 2, h = g & 3;
    const int o0 = OFF[d], dg = CNT[d];
    if (dg == 0) return;
    const float edv = ED[(size_t)d * 4 + h];
    float lc[8];
    float mx = -INFINITY;
    #pragma unroll
    for (int i = 0; i < 8; ++i) {
        if (i < dg) {
            int s = srcsG[o0 + i];
            float lv = ES[(size_t)s * 4 + h] + edv;
            lv = lv > 0.f ? lv : 0.2f * lv;
            lc[i] = lv;
            mx = fmaxf(mx, lv);
        }
    }
    for (int i = 8; i < dg; ++i) {
        int s = srcsG[o0 + i];
        float lv = ES[(size_t)s * 4 + h] + edv;
        lv = lv > 0.f ? lv : 0.2f * lv;
        mx = fmaxf(mx, lv);
    }
    float den = 0.f;
    #pragma unroll
    for (int i = 0; i < 8; ++i) {
        if (i < dg) { lc[i] = __expf(lc[i] - mx); den += lc[i]; }
    }
    for (int i = 8; i < dg; ++i) {
        int s = srcsG[o0 + i];
        float lv = ES[(size_t)s * 4 + h] + edv;
        lv = lv > 0.f ? lv : 0.2f * lv;
        den += __expf(lv - mx);
    }
    const float inv = 1.f / (den + 1e-16f);
    #pragma unroll
    for (int i = 0; i < 8; ++i) {
        if (i < dg) pcsr[(size_t)(o0 + i) * 4 + h] = lc[i] * inv;
    }
    for (int i = 8; i < dg; ++i) {
        int s = srcsG[o0 + i];
        float lv = ES[(size_t)s * 4 + h] + edv;
        lv = lv > 0.f ? lv : 0.2f * lv;
        pcsr[(size_t)(o0 + i) * 4 + h] = __expf(lv - mx) * inv;
    }
}

// ---------------- gather accumulate for one relation (branchless first 4 edges) -----
__device__ __forceinline__ void acc_rel(float a[8], const int* __restrict__ srcsG,
        const float* __restrict__ pcsr, const int* __restrict__ OFF,
        const int* __restrict__ CNT, const u16* __restrict__ HS,
        int ds, bool act, int ln) {
    const int o0 = OFF[ds];
    const int dg = act ? CNT[ds] : 0;
    if (dg == 0) return;
    #pragma unroll
    for (int i = 0; i < 4; ++i) {
        int idx = o0 + (i < dg ? i : dg - 1);
        int s = srcsG[idx];
        float4 p4 = *(const float4*)(pcsr + (size_t)idx * 4);
        uint4 hv  = *(const uint4*)(HS + (size_t)s * 128 + 8 * ln);
        if (i >= dg) { p4.x = 0.f; p4.y = 0.f; p4.z = 0.f; p4.w = 0.f; }
        a[0] += p4.x * bf2f((u16)(hv.x & 0xFFFF)); a[1] += p4.x * bf2f((u16)(hv.x >> 16));
        a[2] += p4.y * bf2f((u16)(hv.y & 0xFFFF)); a[3] += p4.y * bf2f((u16)(hv.y >> 16));
        a[4] += p4.z * bf2f((u16)(hv.z & 0xFFFF)); a[5] += p4.z * bf2f((u16)(hv.z >> 16));
        a[6] += p4.w * bf2f((u16)(hv.w & 0xFFFF)); a[7] += p4.w * bf2f((u16)(hv.w >> 16));
    }
    #pragma unroll
    for (int i = 4; i < 8; ++i) {
        if (i < dg) {
            int idx = o0 + i;
            int s = srcsG[idx];
            float4 p4 = *(const float4*)(pcsr + (size_t)idx * 4);
            uint4 hv  = *(const uint4*)(HS + (size_t)s * 128 + 8 * ln);
            a[0] += p4.x * bf2f((u16)(hv.x & 0xFFFF)); a[1] += p4.x * bf2f((u16)(hv.x >> 16));
            a[2] += p4.y * bf2f((u16)(hv.y & 0xFFFF)); a[3] += p4.y * bf2f((u16)(hv.y >> 16));
            a[4] += p4.z * bf2f((u16)(hv.z & 0xFFFF)); a[5] += p4.z * bf2f((u16)(hv.z >> 16));
            a[6] += p4.w * bf2f((u16)(hv.w & 0xFFFF)); a[7] += p4.w * bf2f((u16)(hv.w >> 16));
        }
    }
    for (int i = 8; i < dg; ++i) {
        int idx = o0 + i;
        int s = srcsG[idx];
        float4 p4 = *(const float4*)(pcsr + (size_t)idx * 4);
        uint4 hv  = *(const uint4*)(HS + (size_t)s * 128 + 8 * ln);
        a[0] += p4.x * bf2f((u16)(hv.x & 0xFFFF)); a[1] += p4.x * bf2f((u16)(hv.x >> 16));
        a[2] += p4.y * bf2f((u16)(hv.y & 0xFFFF)); a[3] += p4.y * bf2f((u16)(hv.y >> 16));
        a[4] += p4.z * bf2f((u16)(hv.z & 0xFFFF)); a[5] += p4.z * bf2f((u16)(hv.z >> 16));
        a[6] += p4.w * bf2f((u16)(hv.w & 0xFFFF)); a[7] += p4.w * bf2f((u16)(hv.w >> 16));
    }
}

// ---------------- merged gather: y=0 -> dst type 0 (rels 1,3,5,7); y=1..4 -> type y.
// OUT_MODE 0: ELU->bf16 perm layout (Xbf). OUT_MODE 2: ELU fp32 un-permuted (d_out),
// LDS-staged for coalesced stores.
template<int OUT_MODE>
__global__ __launch_bounds__(256) void gat_all(
        const int* __restrict__ srcsG, const float* __restrict__ pcsr,
        const int* __restrict__ offs, const int* __restrict__ counts,
        const u16* __restrict__ Hs8, const float* __restrict__ bpermL,
        const float* __restrict__ b0sumL, void* __restrict__ outBase, int N) {
    __shared__ float stg[4][4][128];
    const int y   = blockIdx.y;
    const int tid = threadIdx.x;
    const int ln  = tid & 15;
    const int d   = (blockIdx.x * 256 + tid) >> 4;
    const bool act = (d < N);
    const int ds = act ? d : 0;

    float a[8] = {};
    const float* bb;
    size_t slice;
    if (y == 0) {
        #pragma unroll
        for (int rr = 0; rr < 4; ++rr) {
            const int rel = 2 * rr + 1;
            acc_rel(a, srcsG, pcsr, offs + (size_t)rel * N, counts + (size_t)rel * N,
                    Hs8 + (size_t)rel * N * 128, ds, act, ln);
        }
        bb = b0sumL;
        slice = 0;
    } else {
        const int rel = 2 * (y - 1);
        acc_rel(a, srcsG, pcsr, offs + (size_t)rel * N, counts + (size_t)rel * N,
                Hs8 + (size_t)rel * N * 128, ds, act, ln);
        bb = bpermL + (size_t)rel * 128;
        slice = (size_t)y * N * 128;
    }

    float4 b0 = *(const float4*)(bb + 8 * ln);
    float4 b1 = *(const float4*)(bb + 8 * ln + 4);
    a[0] += b0.x; a[1] += b0.y; a[2] += b0.z; a[3] += b0.w;
    a[4] += b1.x; a[5] += b1.y; a[6] += b1.z; a[7] += b1.w;

    if (OUT_MODE == 0) {
        if (act) {
            u16* OP = (u16*)outBase + slice;
            union { u16 u[8]; uint4 q; } pk;
            #pragma unroll
            for (int j = 0; j < 8; ++j) pk.u[j] = f2bf(eluf(a[j]));
            *(uint4*)(OP + (size_t)d * 128 + 8 * ln) = pk.q;
        }
    } else {
        const int wv = tid >> 6, gl = (tid >> 4) & 3;
        if (act) {
            #pragma unroll
            for (int j = 0; j < 8; ++j)
                stg[wv][gl][(j << 4) | ln] = eluf(a[j]);
        }
        __syncthreads();
        if (act) {
            float* o = (float*)outBase + slice + (size_t)d * 128;
            *(float4*)(o + 8 * ln)     = *(float4*)&stg[wv][gl][8 * ln];
            *(float4*)(o + 8 * ln + 4) = *(float4*)&stg[wv][gl][8 * ln + 4];
        }
    }
}

extern "C" void kernel_launch(void* const* d_in, const int* in_sizes, int n_in,
                              void* d_out, int out_size, void* d_ws, size_t ws_size,
                              hipStream_t stream) {
    const int N = in_sizes[0] / 128;
    const int E = in_sizes[5] / (2 * NRELS);

    const float* xs0[5] = { (const float*)d_in[0], (const float*)d_in[1],
                            (const float*)d_in[2], (const float*)d_in[3],
                            (const float*)d_in[4] };
    const int*   edges = (const int*)d_in[5];
    const float* Ws1 = (const float*)d_in[6];
    const float* Wd1 = (const float*)d_in[7];
    const float* as1 = (const float*)d_in[8];
    const float* ad1 = (const float*)d_in[9];
    const float* b1  = (const float*)d_in[10];
    const float* Ws2 = (const float*)d_in[11];
    const float* Wd2 = (const float*)d_in[12];
    const float* as2 = (const float*)d_in[13];
    const float* ad2 = (const float*)d_in[14];
    const float* b2  = (const float*)d_in[15];
    float* out = (float*)d_out;

    // workspace layout (~417 MB; ws_size ~1 GB)
    char* wp = (char*)d_ws;
    u16*   Xbf   = (u16*)wp;   wp += (size_t)5 * N * 128 * 2;
    u16*   Hs8   = (u16*)wp;   wp += (size_t)8 * N * 128 * 2;
    float* es8   = (float*)wp; wp += (size_t)8 * N * 4 * 4;
    float* ed8   = (float*)wp; wp += (size_t)8 * N * 4 * 4;
    float* pcsr  = (float*)wp; wp += (size_t)NRELS * E * 4 * 4;
    int* counts  = (int*)wp;   wp += (size_t)NRELS * N * 4;
    int* offs    = (int*)wp;   wp += (size_t)NRELS * N * 4;
    int* pos     = (int*)wp;   wp += (size_t)NRELS * N * 4;
    int* srcs    = (int*)wp;   wp += (size_t)NRELS * E * 4;
    u16* Wfrag   = (u16*)wp;   wp += (size_t)16 * 18432 * 2;
    float* bperm = (float*)wp; wp += (size_t)16 * 128 * 4;
    float* b0sum = (float*)wp; wp += (size_t)2 * 128 * 4;
    int* bsum    = (int*)wp;   wp += 1024 * 4;
    int* bpref   = (int*)wp;   wp += 1024 * 4;
    const size_t ws_used = (size_t)(wp - (char*)d_ws);
    if (ws_used > ws_size) return;

    // ---- zero ONLY the atomic histogram (write-before-read audit holds elsewhere) --
    const int M = NRELS * N;
    hipMemsetAsync(counts, 0, (size_t)M * 4, stream);

    const int nEB = (E + 255) / 256;
    const int eblocks = 8 * nEB;

    // ---- prep weights + b0sum + histogram, one dispatch ----
    prep_hist<<<dim3(18 + eblocks), 256, 0, stream>>>(
        Ws1, Wd1, as1, ad1, b1, Ws2, Wd2, as2, ad2, b2,
        Wfrag, bperm, b0sum, edges, counts, E, N);

    // ---- scan chain ----
    const int nb = (M + 2047) / 2048;
    scan_block_k<<<dim3(nb), 256, 0, stream>>>(counts, offs, bsum, M);
    scan_tops_k<<<dim3(1), 1024, 0, stream>>>(bsum, bpref, nb);
    scan_add_k<<<dim3((M + 255) / 256), 256, 0, stream>>>(offs, pos, bpref, M);

    const int gemmBlocks  = (N + 127) / 128;
    const int G6          = gemmBlocks * 6;
    const int gBlocks     = (N + 15) / 16;
    const int pnormBlocks = (N * 4 + 255) / 256;

    // interleave period: 1 gemm block per 3; K gemm slots, 2K build slots
    const int K = (G6 > (eblocks + 1) / 2) ? G6 : (eblocks + 1) / 2;

    for (int layer = 0; layer < 2; ++layer) {
        const u16*   WL = Wfrag + (size_t)layer * 8 * 18432;
        const float* bL = bperm + layer * 8 * 128;

        if (layer == 0) {
            // layer-1 gemm (fp32 inputs) concurrent with CSR build
            gemm1_build<<<dim3(3 * K), 256, 0, stream>>>(
                xs0[0], xs0[1], xs0[2], xs0[3], xs0[4],
                WL, Hs8, es8, ed8, edges, pos, srcs, gemmBlocks, E, N);
        } else {
            gemm2_mfma<<<dim3(gemmBlocks, 6), 256, 0, stream>>>(
                Xbf, WL, Hs8, es8, ed8, N);
        }

        pnorm_k<<<dim3(pnormBlocks, 8), 256, 0, stream>>>(
            srcs, offs, counts, es8, ed8, pcsr, N);

        if (layer == 0)
            gat_all<0><<<dim3(gBlocks, 5), 256, 0, stream>>>(
                srcs, pcsr, offs, counts, Hs8, bL, b0sum + 0 * 128, Xbf, N);
        else
            gat_all<2><<<dim3(gBlocks, 5), 256, 0, stream>>>(
                srcs, pcsr, offs, counts, Hs8, bL, b0sum + 1 * 128, out, N);
    }
}